// Round 3
// baseline (237.853 us; speedup 1.0000x reference)
//
#include <hip/hip_runtime.h>
#include <math.h>

// RPNLayer: logits = x(32768,1024) @ W(1024,16) + b; per-anchor (8) 2-class
// log-softmax CE over valid anchors; argmax + candidate mask.
//
// R3 structure: barrier-free main loop.
//   - Block = 512 threads = 8 waves; 64 rows per block; grid 512.
//   - Wave ks owns K-slice [ks*128, ks*128+128); lane = row (64 rows/wave),
//     each lane accumulates all 16 channels -> W index is WAVE-UNIFORM, so
//     W comes in via s_load (scalar pipe), not LDS. Inner loop LDS traffic:
//     8 ds_read_b128 per 512 FMAs (was 72 per 256 in R2).
//   - Each wave stages x chunks into its PRIVATE LDS slab and reads only its
//     own slab: no __syncthreads in the main loop. Next chunk is prefetched
//     into registers during compute (latency hidden under FMA issue).
//   - 2 barriers total: around the 8-way cross-wave K-reduction in LDS.
//
// d_out (float32): [0] loss | [1..262144] predict | [262145..524288] mask

#define ROWS   64            // rows per block (= lanes per wave)
#define NW     8             // waves per block = K-split factor
#define KSLICE 128           // K per wave
#define CHUNK  32            // K per staged chunk
#define NCH    (KSLICE/CHUNK)   // 4
#define XSTR   36            // padded LDS row stride in floats (144 B)
#define RSTR   136           // reduction row stride: 8*16 + 8 pad

__global__ __launch_bounds__(512, 4)
void rpn_main(const float* __restrict__ x, const float* __restrict__ W,
              const float* __restrict__ b, const int* __restrict__ lab,
              float* __restrict__ out, float* __restrict__ ws)
{
    __shared__ float xs[NW * ROWS * XSTR];   // 18432 floats = 73728 B
    float* red = xs;                         // aliased: lifetimes disjoint

    const int tid  = threadIdx.x;
    const int lane = tid & 63;
    const int ks   = __builtin_amdgcn_readfirstlane(tid >> 6);
    const int row0 = blockIdx.x * ROWS;

    float* slab = xs + ks * (ROWS * XSTR);
    const float* gbase = x + (size_t)row0 * 1024 + ks * KSLICE;

    float acc[16];
#pragma unroll
    for (int c = 0; c < 16; ++c) acc[c] = 0.f;

    // prefetch chunk 0 into registers
    float4 pf[8];
#pragma unroll
    for (int j = 0; j < 8; ++j) {
        int fl = j * 64 + lane;              // 512 float4s: 64 rows x 8
        pf[j] = *(const float4*)(gbase + (size_t)(fl >> 3) * 1024 + (fl & 7) * 4);
    }

#pragma unroll 1
    for (int ch = 0; ch < NCH; ++ch) {
        // ---- spill prefetched chunk into this wave's private slab ----
#pragma unroll
        for (int j = 0; j < 8; ++j) {
            int fl = j * 64 + lane;
            *(float4*)(slab + (fl >> 3) * XSTR + (fl & 7) * 4) = pf[j];
        }
        // ---- issue next chunk's global loads (hidden under compute) ----
        if (ch + 1 < NCH) {
            const float* g = gbase + (ch + 1) * CHUNK;
#pragma unroll
            for (int j = 0; j < 8; ++j) {
                int fl = j * 64 + lane;
                pf[j] = *(const float4*)(g + (size_t)(fl >> 3) * 1024 + (fl & 7) * 4);
            }
        }
        // ---- compute: lane = row, 16 channels, W via scalar loads ----
        const float* xrow = slab + lane * XSTR;
        const float* wk   = W + (size_t)(ks * KSLICE + ch * CHUNK) * 16;
#pragma unroll
        for (int t4 = 0; t4 < 8; ++t4) {
            float4 xq = *(const float4*)(xrow + t4 * 4);
#pragma unroll
            for (int i = 0; i < 4; ++i) {
                float xv = (&xq.x)[i];
                const float* wr = wk + (t4 * 4 + i) * 16;   // wave-uniform
#pragma unroll
                for (int c = 0; c < 16; ++c)
                    acc[c] = fmaf(xv, wr[c], acc[c]);
            }
        }
    }

    // ---- 8-way K reduction across waves via LDS (red aliases xs) ----
    __syncthreads();
    {
        float* rp = red + lane * RSTR + ks * 16;
        *(float4*)(rp + 0)  = make_float4(acc[0],  acc[1],  acc[2],  acc[3]);
        *(float4*)(rp + 4)  = make_float4(acc[4],  acc[5],  acc[6],  acc[7]);
        *(float4*)(rp + 8)  = make_float4(acc[8],  acc[9],  acc[10], acc[11]);
        *(float4*)(rp + 12) = make_float4(acc[12], acc[13], acc[14], acc[15]);
    }
    __syncthreads();

    // ---- epilogue: one thread per row (wave 0 only) ----
    if (tid < ROWS) {
        const int row = row0 + tid;
        float L[16];
#pragma unroll
        for (int c = 0; c < 16; ++c) {
            float s = 0.f;
#pragma unroll
            for (int k = 0; k < NW; ++k) s += red[tid * RSTR + k * 16 + c];
            L[c] = s + b[c];
        }

        const int* labp  = lab + (size_t)row * 8;
        float*     predp = out + 1 + (size_t)row * 8;
        float*     maskp = out + 1 + 262144 + (size_t)row * 8;

        float lsum = 0.f, lcnt = 0.f;
#pragma unroll
        for (int a = 0; a < 8; ++a) {
            float l0 = L[2 * a], l1 = L[2 * a + 1];
            int   lb = labp[a];
            int   pred  = (l1 > l0) ? 1 : 0;          // strict: tie -> class 0
            int   valid = (lb != -1);
            float m   = fmaxf(l0, l1);
            float lse = m + logf(expf(l0 - m) + expf(l1 - m));
            float nll = lse - ((lb == 1) ? l1 : l0);
            if (valid) { lsum += nll; lcnt += 1.f; }
            predp[a] = (float)pred;
            maskp[a] = (pred && valid) ? 1.f : 0.f;
        }

        // tid<64 == wave 0: full-wave shuffle reduction
#pragma unroll
        for (int off = 32; off > 0; off >>= 1) {
            lsum += __shfl_down(lsum, off, 64);
            lcnt += __shfl_down(lcnt, off, 64);
        }
        if (tid == 0) {
            atomicAdd(&ws[0], lsum);
            atomicAdd(&ws[1], lcnt);
        }
    }
}

__global__ void rpn_final(const float* __restrict__ ws, float* __restrict__ out)
{
    out[0] = ws[0] / fmaxf(ws[1], 1.f);
}

extern "C" void kernel_launch(void* const* d_in, const int* in_sizes, int n_in,
                              void* d_out, int out_size, void* d_ws, size_t ws_size,
                              hipStream_t stream)
{
    const float* x   = (const float*)d_in[0];   // (64,512,1024) f32
    const float* W   = (const float*)d_in[1];   // (1024,16) f32
    const float* b   = (const float*)d_in[2];   // (16,) f32
    const int*   lab = (const int*)d_in[3];     // (64,512,8) i32 in {-1,0,1}
    float* out = (float*)d_out;
    float* ws  = (float*)d_ws;

    hipMemsetAsync(ws, 0, 2 * sizeof(float), stream);
    rpn_main<<<dim3(512), dim3(512), 0, stream>>>(x, W, b, lab, out, ws);
    rpn_final<<<dim3(1), dim3(1), 0, stream>>>(ws, out);
}

// Round 4
// 211.799 us; speedup vs baseline: 1.1230x; 1.1230x over previous
//
#include <hip/hip_runtime.h>
#include <math.h>

// RPNLayer: logits = x(32768,1024) @ W(1024,16) + b; per-anchor (8) 2-class
// log-softmax CE over valid anchors; argmax + candidate mask.
//
// R4 structure: no-LDS main loop, direct per-lane row reads.
//   - R3 post-mortem: __launch_bounds__(512,4) capped the allocator (~52
//     VGPRs) and spilled pf[8] -> 123 MB of scratch WRITE traffic. Fix:
//     shrink working set (pf[4], 16-k chunks) and relax bounds to (512,2).
//   - lane = row (64 rows/wave), wave ks owns K-slice [ks*128, ks*128+128).
//     W index is wave-uniform (readfirstlane) -> scalar s_load pipe.
//   - x is read DIRECTLY from global per-lane: each lane reads only its own
//     row, so LDS staging/transpose buys nothing. Per 16-k chunk a lane
//     reads one 64B line via 4 dwordx4 loads (back-to-back reuse, no
//     over-fetch). 1-chunk register prefetch (pf[4] = 16 VGPRs) hides
//     latency under 256 FMAs; 16 waves/CU TLP covers the rest.
//   - No barriers in the main loop; LDS (34 KB) only for the final 8-way
//     cross-wave K-reduction.
//
// d_out (float32): [0] loss | [1..262144] predict | [262145..524288] mask

#define ROWS   64            // rows per block (= lanes per wave)
#define NW     8             // waves per block = K-split factor
#define KSLICE 128           // K per wave
#define KCH    16            // K per chunk (one 64B line per lane)
#define NCH    (KSLICE/KCH)  // 8
#define RSTR   136           // reduction row stride: 8*16 + 8 pad

__global__ __launch_bounds__(512, 2)
void rpn_main(const float* __restrict__ x, const float* __restrict__ W,
              const float* __restrict__ b, const int* __restrict__ lab,
              float* __restrict__ out, float* __restrict__ ws)
{
    __shared__ float red[ROWS * RSTR];       // 8704 floats = 34816 B

    const int tid  = threadIdx.x;
    const int lane = tid & 63;
    const int ks   = __builtin_amdgcn_readfirstlane(tid >> 6);
    const int row0 = blockIdx.x * ROWS;

    const float* xp = x + (size_t)(row0 + lane) * 1024 + ks * KSLICE;
    const float* wk = W + (size_t)(ks * KSLICE) * 16;

    float acc[16];
#pragma unroll
    for (int c = 0; c < 16; ++c) acc[c] = 0.f;

    // prefetch chunk 0: 16 k = 4 float4 (one 64B line)
    float4 pf[4];
#pragma unroll
    for (int j = 0; j < 4; ++j) pf[j] = *(const float4*)(xp + j * 4);

#define FMA16(V, WROW)                                            \
    do {                                                          \
        const float* _w = (WROW);                                 \
        _Pragma("unroll")                                         \
        for (int c = 0; c < 16; ++c)                              \
            acc[c] = fmaf((V), _w[c], acc[c]);                    \
    } while (0)

#pragma unroll 1
    for (int ch = 0; ch < NCH - 1; ++ch) {
        const float* wc = wk + ch * KCH * 16;
        const float* gn = xp + (ch + 1) * KCH;
#pragma unroll
        for (int j = 0; j < 4; ++j) {
            float4 v = pf[j];
            pf[j] = *(const float4*)(gn + j * 4);   // issue next-chunk load
            FMA16(v.x, wc + (j * 4 + 0) * 16);
            FMA16(v.y, wc + (j * 4 + 1) * 16);
            FMA16(v.z, wc + (j * 4 + 2) * 16);
            FMA16(v.w, wc + (j * 4 + 3) * 16);
        }
    }
    {   // tail chunk: compute only
        const float* wc = wk + (NCH - 1) * KCH * 16;
#pragma unroll
        for (int j = 0; j < 4; ++j) {
            float4 v = pf[j];
            FMA16(v.x, wc + (j * 4 + 0) * 16);
            FMA16(v.y, wc + (j * 4 + 1) * 16);
            FMA16(v.z, wc + (j * 4 + 2) * 16);
            FMA16(v.w, wc + (j * 4 + 3) * 16);
        }
    }
#undef FMA16

    // ---- 8-way K reduction across waves via LDS ----
    __syncthreads();   // not strictly needed pre-write (private slots), keeps ordering simple
    {
        float* rp = red + lane * RSTR + ks * 16;
        *(float4*)(rp + 0)  = make_float4(acc[0],  acc[1],  acc[2],  acc[3]);
        *(float4*)(rp + 4)  = make_float4(acc[4],  acc[5],  acc[6],  acc[7]);
        *(float4*)(rp + 8)  = make_float4(acc[8],  acc[9],  acc[10], acc[11]);
        *(float4*)(rp + 12) = make_float4(acc[12], acc[13], acc[14], acc[15]);
    }
    __syncthreads();

    // ---- epilogue: one thread per row (wave 0 only) ----
    if (tid < ROWS) {
        const int row = row0 + tid;
        float L[16];
#pragma unroll
        for (int c = 0; c < 16; ++c) {
            float s = 0.f;
#pragma unroll
            for (int k = 0; k < NW; ++k) s += red[tid * RSTR + k * 16 + c];
            L[c] = s + b[c];
        }

        const int* labp  = lab + (size_t)row * 8;
        float*     predp = out + 1 + (size_t)row * 8;
        float*     maskp = out + 1 + 262144 + (size_t)row * 8;

        float lsum = 0.f, lcnt = 0.f;
#pragma unroll
        for (int a = 0; a < 8; ++a) {
            float l0 = L[2 * a], l1 = L[2 * a + 1];
            int   lb = labp[a];
            int   pred  = (l1 > l0) ? 1 : 0;          // strict: tie -> class 0
            int   valid = (lb != -1);
            float m   = fmaxf(l0, l1);
            float lse = m + logf(expf(l0 - m) + expf(l1 - m));
            float nll = lse - ((lb == 1) ? l1 : l0);
            if (valid) { lsum += nll; lcnt += 1.f; }
            predp[a] = (float)pred;
            maskp[a] = (pred && valid) ? 1.f : 0.f;
        }

        // tid<64 == wave 0: full-wave shuffle reduction
#pragma unroll
        for (int off = 32; off > 0; off >>= 1) {
            lsum += __shfl_down(lsum, off, 64);
            lcnt += __shfl_down(lcnt, off, 64);
        }
        if (tid == 0) {
            atomicAdd(&ws[0], lsum);
            atomicAdd(&ws[1], lcnt);
        }
    }
}

__global__ void rpn_final(const float* __restrict__ ws, float* __restrict__ out)
{
    out[0] = ws[0] / fmaxf(ws[1], 1.f);
}

extern "C" void kernel_launch(void* const* d_in, const int* in_sizes, int n_in,
                              void* d_out, int out_size, void* d_ws, size_t ws_size,
                              hipStream_t stream)
{
    const float* x   = (const float*)d_in[0];   // (64,512,1024) f32
    const float* W   = (const float*)d_in[1];   // (1024,16) f32
    const float* b   = (const float*)d_in[2];   // (16,) f32
    const int*   lab = (const int*)d_in[3];     // (64,512,8) i32 in {-1,0,1}
    float* out = (float*)d_out;
    float* ws  = (float*)d_ws;

    hipMemsetAsync(ws, 0, 2 * sizeof(float), stream);
    rpn_main<<<dim3(512), dim3(512), 0, stream>>>(x, W, b, lab, out, ws);
    rpn_final<<<dim3(1), dim3(1), 0, stream>>>(ws, out);
}